// Round 4
// baseline (20776.689 us; speedup 1.0000x reference)
//
#include <hip/hip_runtime.h>
#include <math.h>

// ---------------------------------------------------------------------------
// R15: latency-exposure attack. R14 post-mortem: 3 different kernels all at
// ~46Kcy/step vs ~15Kcy of countable work; VALUBusy == fma density; 1
// wave/SIMD (Occupancy 12%) => every LLC RT / LDS latency / poll is serially
// exposed. This round:
//   - 512 threads (8 waves = 2/SIMD): wave = (batch-quarter w&3, K-half
//     w>>2). Per-wave w-reads and h-reads halve => total LDS instrs ~= R14,
//     per-wave VALU halves, 2-way TLP hides latency. K-half partials merge
//     via a small LDS exchange (xbuf) between wave pairs (w, w+4).
//   - bank-conflict fix (R14's 314M conflicts): lane unit ownership strides
//     by ONE padded 772/388-float row (u = usl + 8i) => usl-groups at 16B
//     mod 128B, the R11-proven conflict-free pattern.
//   - ih2/ih3 weights into LDS (fit; removes per-step L2 streams). ih4 stays
//     global-streamed (doesn't fit with hh4-resident).
//   - hst/ring_store dropped (R13: store coalescing is time-neutral);
//     direct 4B agent-scope stores. Pays LDS budget for xbuf.
// Transport unchanged: sc0 sc1 LLC loads, agent-scope atomic stores,
// vmcnt(0)+barrier before flag; wave0-only cached polls; bounded spins.
// ---------------------------------------------------------------------------

__device__ __forceinline__ float sigmoidf_(float v) {
    return 1.0f / (1.0f + __expf(-v));
}
__device__ __forceinline__ float tanhf_(float v) {
    float e = __expf(2.0f * v);
    return 1.0f - 2.0f / (e + 1.0f);
}

// src[(g*H+u)*J + j] -> dst[(u*3+g)*J + j]
__global__ void prep_k(const float* __restrict__ src, float* __restrict__ dst,
                       int H, int J) {
    int idx = blockIdx.x * 256 + threadIdx.x;
    int total = 3 * H * J;
    if (idx < total) {
        int g = idx / (H * J);
        int rem = idx - g * H * J;
        int u = rem / J;
        int j = rem - u * J;
        dst[(u * 3 + g) * J + j] = src[(g * H + u) * J + j];
    }
}

// ---- transport primitives --------------------------------------------------

__device__ __forceinline__ void flag_st(int* p, int v) {
    __hip_atomic_store(p, v, __ATOMIC_RELAXED, __HIP_MEMORY_SCOPE_AGENT);
}
__device__ __forceinline__ int flag_ld(const int* p) {
    return __hip_atomic_load(p, __ATOMIC_RELAXED, __HIP_MEMORY_SCOPE_AGENT);
}
__device__ __forceinline__ void ex_store(float* p, float v) {
    __hip_atomic_store(p, v, __ATOMIC_RELAXED, __HIP_MEMORY_SCOPE_AGENT);
}

// wave0-only poll with monotonic per-lane flag cache; barrier for the block.
__device__ __forceinline__ void pollwait(const int* p, int tgt, bool active,
                                         int& fc) {
    if (threadIdx.x < 64) {
        bool need = active && (fc < tgt);
        if (__any(need)) {
            int spins = 0;
            while (true) {
                if (need) { fc = flag_ld(p); need = (fc < tgt); }
                if (!__any(need)) break;
                if (++spins > 200000) break;  // degrade to absmax diagnostic
                __builtin_amdgcn_s_sleep(1);
            }
        }
    }
    __syncthreads();
}

// ---- ring staging: 8 rows of J floats, wave-linear (dup'd by kh partner) --

template <int J>
__device__ __forceinline__ void stage8(float* dst, const float* src) {
    constexpr int NF4 = J / 32;  // 8*J/4 float4 over 64 lanes
    const int lane = threadIdx.x & 63;
    float4 tmp[NF4];
    #pragma unroll
    for (int k = 0; k < NF4; ++k) {
        const float* p = src + (size_t)(k * 64 + lane) * 4;
        asm volatile("global_load_dwordx4 %0, %1, off sc0 sc1"
                     : "=v"(tmp[k]) : "v"(p) : "memory");
    }
    asm volatile("s_waitcnt vmcnt(0)" ::: "memory");
    #pragma unroll
    for (int k = 0; k < NF4; ++k)
        *(float4*)(dst + (k * 64 + lane) * 4) = tmp[k];
}

template <int J>
__device__ __forceinline__ void zero8(float* dst) {
    const int lane = threadIdx.x & 63;
    #pragma unroll
    for (int k = 0; k < J / 32; ++k)
        *(float4*)(dst + (k * 64 + lane) * 4) = make_float4(0.f, 0.f, 0.f, 0.f);
}

// ---- register-tiled dots, lane = (usl 0..7, kl 0..7), wave K-half kh ------
// dotA: 4 units {usl+8i}, 8 batches. a[g][f]: g = i*2+(b>>2),
//       f = (ch<2?ch:NCH3)*4 + (b&3). Unit rows stride WST (772 => 16B mod
//       128B across usl: conflict-free).
template <int J, int WST, int NCH3, int F>
__device__ __forceinline__ void dotA(const float* __restrict__ wb,
                                     const float* __restrict__ hb,
                                     int kh, int kl, float (&a)[8][F]) {
    #pragma unroll
    for (int itl = 0; itl < J / 64; ++itl) {
        const int j = ((kh * (J / 64) + itl) * 8 + kl) * 4;
        float4 h4[8];
        #pragma unroll
        for (int b = 0; b < 8; ++b) h4[b] = *(const float4*)(hb + b * J + j);
        #pragma unroll
        for (int i = 0; i < 4; ++i) {
            #pragma unroll
            for (int ch = 0; ch < 3; ++ch) {
                float4 wv = *(const float4*)(wb + i * 8 * WST + ch * J + j);
                const int fb = (ch < 2 ? ch : NCH3) * 4;
                #pragma unroll
                for (int b = 0; b < 8; ++b) {
                    float& acc = a[i * 2 + (b >> 2)][fb + (b & 3)];
                    acc = fmaf(wv.x, h4[b].x, acc);
                    acc = fmaf(wv.y, h4[b].y, acc);
                    acc = fmaf(wv.z, h4[b].z, acc);
                    acc = fmaf(wv.w, h4[b].w, acc);
                }
            }
        }
    }
}

// dotB: 2 units {usl+8i}, 8 batches. a[g][f]: g = i*4+(b>>1),
//       f = (ch<2?ch:NCH3)*2 + (b&1).
template <int J, int WST, int NCH3>
__device__ __forceinline__ void dotB(const float* __restrict__ wb,
                                     const float* __restrict__ hb,
                                     int kh, int kl, float (&a)[8][8]) {
    #pragma unroll
    for (int itl = 0; itl < J / 64; ++itl) {
        const int j = ((kh * (J / 64) + itl) * 8 + kl) * 4;
        float4 h4[8];
        #pragma unroll
        for (int b = 0; b < 8; ++b) h4[b] = *(const float4*)(hb + b * J + j);
        #pragma unroll
        for (int i = 0; i < 2; ++i) {
            #pragma unroll
            for (int ch = 0; ch < 3; ++ch) {
                float4 wv = *(const float4*)(wb + i * 8 * WST + ch * J + j);
                const int fb = (ch < 2 ? ch : NCH3) * 2;
                #pragma unroll
                for (int b = 0; b < 8; ++b) {
                    float& acc = a[i * 4 + (b >> 1)][fb + (b & 1)];
                    acc = fmaf(wv.x, h4[b].x, acc);
                    acc = fmaf(wv.y, h4[b].y, acc);
                    acc = fmaf(wv.z, h4[b].z, acc);
                    acc = fmaf(wv.w, h4[b].w, acc);
                }
            }
        }
    }
}

// Reduce-scatter over the 8 kl-lanes; lane ends owning group
// gf = (kl0<<2)|(kl1<<1)|kl2 in a[0][*].
template <int F>
__device__ __forceinline__ void rscat8(float (&a)[8][F], int kl) {
    #pragma unroll
    for (int lev = 0; lev < 3; ++lev) {
        const int m = 1 << lev;
        const int g = 8 >> (lev + 1);
        const bool hi = ((kl >> lev) & 1) != 0;
        #pragma unroll
        for (int gg = 0; gg < g; ++gg) {
            #pragma unroll
            for (int f = 0; f < F; ++f) {
                float give = hi ? a[gg][f] : a[gg + g][f];
                float got = __shfl_xor(give, m, 64);
                a[gg][f] = (hi ? a[gg + g][f] : a[gg][f]) + got;
            }
        }
    }
}

// K-half merge: waves 4..7 publish NF finals, waves 0..3 accumulate.
template <int F, int F0, int NF>
__device__ __forceinline__ void khmerge(float* xb, float (&a)[8][F],
                                        int w, int lane) {
    if (w >= 4) {
        #pragma unroll
        for (int k = 0; k < NF; ++k)
            xb[((w - 4) * 64 + lane) * 8 + k] = a[0][F0 + k];
    }
    __syncthreads();
    if (w < 4) {
        #pragma unroll
        for (int k = 0; k < NF; ++k)
            a[0][F0 + k] += xb[(w * 64 + lane) * 8 + k];
    }
    __syncthreads();
}

__global__ __launch_bounds__(512) void gru_pipe_kernel(
    const float* __restrict__ x,
    const float* __restrict__ w_ih1,
    const float* __restrict__ b_ih1, const float* __restrict__ b_hh1,
    const float* __restrict__ b_ih2, const float* __restrict__ b_hh2,
    const float* __restrict__ b_ih3, const float* __restrict__ b_hh3,
    const float* __restrict__ b_ih4, const float* __restrict__ b_hh4,
    const float* __restrict__ wA_hh1,  // [256][3][256]
    const float* __restrict__ wA_ih2,  // [128][3][256]
    const float* __restrict__ wA_hh2,  // [128][3][128]
    const float* __restrict__ wA_ih3,  // [128][3][128]
    const float* __restrict__ wA_hh3,  // [128][3][128]
    const float* __restrict__ wA_ih4,  // [256][3][128]
    const float* __restrict__ wA_hh4,  // [256][3][256]
    const float* __restrict__ w_out, const float* __restrict__ b_out,
    int* __restrict__ flags,  // [8 bg][4 stages x 32 ints]
    float* __restrict__ ex,   // [8 bg][98304] h rings
    float* __restrict__ out)  // [256][1024] pre-zeroed
{
    const int tid = threadIdx.x;
    const int lane = tid & 63;
    const int w = tid >> 6;        // wave 0..7
    const int bh = w & 3;          // batch quarter (8 rows)
    const int kh = w >> 2;         // K half
    const int usl = lane >> 3;     // unit slot 0..7
    const int kl = lane & 7;       // K slice 0..7
    extern __shared__ float smem[];
    __shared__ float xs[32];

    const int bg = blockIdx.x & 7;
    const int rest = blockIdx.x >> 3;
    const int s = rest >> 3;       // stage 0..3
    const int us = rest & 7;       // unit slice 0..7

    int* fbp = flags + bg * 128;
    int* arr_own = fbp + s * 32;

    // wave0 poll roles (R11-proven)
    const int* pT = arr_own; int dT = -1000000000; bool aT = false;
    const int* pM = arr_own; bool aM = false;
    if (tid < 8) {
        if (s > 0) { pT = fbp + (s - 1) * 32 + tid; dT = 1; aT = true; }
        pM = arr_own + tid; aM = true;
    } else if (tid < 16) {
        if (s < 3) { pT = fbp + (s + 1) * 32 + (tid - 8); dT = -3; aT = true; }
    }
    int fcT = 0, fcM = 0;

    float* exb = ex + (size_t)bg * 98304;
    float* h1r = exb;            // 4 x 32 x 256
    float* h2r = exb + 32768;    // 4 x 32 x 128
    float* h3r = exb + 49152;
    float* h4r = exb + 65536;

    if (s == 0) {
        // ---- layer 1: in=1 scalar, H=256 ----
        float* wlds = smem;             // 32 x 772
        float* hprev = smem + 24704;    // 32 x 256
        float* xb = smem + 32896;       // 4 x 64 x 8
        {
            const float* srcw = wA_hh1 + (size_t)us * 32 * 768;
            for (int i = tid; i < 24576; i += 512) {
                int uu = i / 768, r = i - uu * 768;
                wlds[uu * 772 + r] = srcw[i];
            }
        }
        __syncthreads();
        const int iown = ((kl & 1) << 1) | ((kl >> 1) & 1);
        const int k2 = (kl >> 2) & 1;
        const int ul = usl + 8 * iown;
        const int u = us * 32 + ul;
        const float* wbh = wlds + usl * 772;
        const float* hbh = hprev + bh * 2048;
        const float br = b_ih1[u] + b_hh1[u];
        const float bz = b_ih1[u + 256] + b_hh1[u + 256];
        const float bxn = b_ih1[u + 512];
        const float bhn = b_hh1[u + 512];
        const float wir = w_ih1[u], wiz = w_ih1[u + 256], win = w_ih1[u + 512];
        for (int t = 0; t < 1024; ++t) {
            pollwait(pT, t + dT, aT, fcT);     // downstream backpressure
            if (tid < 32) xs[tid] = x[(size_t)(bg * 32 + tid) * 1024 + t];
            pollwait(pM, t, aM, fcM);          // peers done t-1
            if (t > 0) stage8<256>(hprev + bh * 2048,
                                   h1r + (size_t)((t - 1) & 3) * 8192 + bh * 2048);
            else       zero8<256>(hprev + bh * 2048);
            float a[8][12] = {};
            dotA<256, 772, 2, 12>(wbh, hbh, kh, kl, a);   // hn -> slots 8..11
            rscat8<12>(a, kl);
            khmerge<12, 0, 8>(xb, a, w, lane);
            khmerge<12, 8, 4>(xb, a, w, lane);
            if (w < 4) {
                float* hout = h1r + (size_t)(t & 3) * 8192;
                #pragma unroll
                for (int bl = 0; bl < 4; ++bl) {
                    int b32 = bh * 8 + k2 * 4 + bl;
                    float xv = xs[b32];
                    float rr = sigmoidf_(a[0][bl] + br + xv * wir);
                    float zz = sigmoidf_(a[0][4 + bl] + bz + xv * wiz);
                    float nn = tanhf_(xv * win + bxn + rr * (a[0][8 + bl] + bhn));
                    float hp = hprev[b32 * 256 + u];
                    ex_store(hout + b32 * 256 + u, (1.f - zz) * nn + zz * hp);
                }
            }
            asm volatile("s_waitcnt vmcnt(0)" ::: "memory");
            __syncthreads();
            if (tid == 0) flag_st(arr_own + us, t + 1);
        }
    } else if (s == 1) {
        // ---- layer 2: in=256, H=128 ----
        float* whhL = smem;             // 16 x 388
        float* wihL = smem + 6208;      // 16 x 772
        float* hin = smem + 18560;      // 32 x 256
        float* hprev = smem + 26752;    // 32 x 128
        float* xb = smem + 30848;       // 4 x 64 x 8
        {
            const float* srcw = wA_hh2 + (size_t)us * 16 * 384;
            for (int i = tid; i < 6144; i += 512) {
                int uu = i / 384, r = i - uu * 384;
                whhL[uu * 388 + r] = srcw[i];
            }
            const float* srci = wA_ih2 + (size_t)us * 16 * 768;
            for (int i = tid; i < 12288; i += 512) {
                int uu = i / 768, r = i - uu * 768;
                wihL[uu * 772 + r] = srci[i];
            }
        }
        __syncthreads();
        const int iown = kl & 1;
        const int bq = (kl & 2) | ((kl >> 2) & 1);   // (kl1<<1)|kl2
        const int ul = usl + 8 * iown;
        const int u = us * 16 + ul;
        const float* wbi = wihL + usl * 772;
        const float* wbh = whhL + usl * 388;
        const float br = b_ih2[u] + b_hh2[u];
        const float bz = b_ih2[u + 128] + b_hh2[u + 128];
        const float bxn = b_ih2[u + 256];
        const float bhn = b_hh2[u + 256];
        for (int t = 0; t < 1024; ++t) {
            pollwait(pT, t + dT, aT, fcT);   // upstream >= t+1, down >= t-3
            stage8<256>(hin + bh * 2048, h1r + (size_t)(t & 3) * 8192 + bh * 2048);
            float a[8][8] = {};
            dotB<256, 772, 2>(wbi, hin + bh * 2048, kh, kl, a);
            pollwait(pM, t, aM, fcM);
            if (t > 0) stage8<128>(hprev + bh * 1024,
                                   h2r + (size_t)((t - 1) & 3) * 4096 + bh * 1024);
            else       zero8<128>(hprev + bh * 1024);
            dotB<128, 388, 3>(wbh, hprev + bh * 1024, kh, kl, a);
            rscat8<8>(a, kl);
            khmerge<8, 0, 8>(xb, a, w, lane);
            if (w < 4) {
                float* hout = h2r + (size_t)(t & 3) * 4096;
                #pragma unroll
                for (int bl = 0; bl < 2; ++bl) {
                    int b32 = bh * 8 + bq * 2 + bl;
                    float rr = sigmoidf_(a[0][bl] + br);
                    float zz = sigmoidf_(a[0][2 + bl] + bz);
                    float nn = tanhf_(a[0][4 + bl] + bxn + rr * (a[0][6 + bl] + bhn));
                    float hp = hprev[b32 * 128 + u];
                    ex_store(hout + b32 * 128 + u, (1.f - zz) * nn + zz * hp);
                }
            }
            asm volatile("s_waitcnt vmcnt(0)" ::: "memory");
            __syncthreads();
            if (tid == 0) flag_st(arr_own + us, t + 1);
        }
    } else if (s == 2) {
        // ---- layer 3: in=128, H=128 ----
        float* whhL = smem;             // 16 x 388
        float* wihL = smem + 6208;      // 16 x 388
        float* hin = smem + 12416;      // 32 x 128
        float* hprev = smem + 16512;    // 32 x 128
        float* xb = smem + 20608;       // 4 x 64 x 8
        {
            const float* srcw = wA_hh3 + (size_t)us * 16 * 384;
            for (int i = tid; i < 6144; i += 512) {
                int uu = i / 384, r = i - uu * 384;
                whhL[uu * 388 + r] = srcw[i];
            }
            const float* srci = wA_ih3 + (size_t)us * 16 * 384;
            for (int i = tid; i < 6144; i += 512) {
                int uu = i / 384, r = i - uu * 384;
                wihL[uu * 388 + r] = srci[i];
            }
        }
        __syncthreads();
        const int iown = kl & 1;
        const int bq = (kl & 2) | ((kl >> 2) & 1);
        const int ul = usl + 8 * iown;
        const int u = us * 16 + ul;
        const float* wbi = wihL + usl * 388;
        const float* wbh = whhL + usl * 388;
        const float br = b_ih3[u] + b_hh3[u];
        const float bz = b_ih3[u + 128] + b_hh3[u + 128];
        const float bxn = b_ih3[u + 256];
        const float bhn = b_hh3[u + 256];
        for (int t = 0; t < 1024; ++t) {
            pollwait(pT, t + dT, aT, fcT);
            stage8<128>(hin + bh * 1024, h2r + (size_t)(t & 3) * 4096 + bh * 1024);
            float a[8][8] = {};
            dotB<128, 388, 2>(wbi, hin + bh * 1024, kh, kl, a);
            pollwait(pM, t, aM, fcM);
            if (t > 0) stage8<128>(hprev + bh * 1024,
                                   h3r + (size_t)((t - 1) & 3) * 4096 + bh * 1024);
            else       zero8<128>(hprev + bh * 1024);
            dotB<128, 388, 3>(wbh, hprev + bh * 1024, kh, kl, a);
            rscat8<8>(a, kl);
            khmerge<8, 0, 8>(xb, a, w, lane);
            if (w < 4) {
                float* hout = h3r + (size_t)(t & 3) * 4096;
                #pragma unroll
                for (int bl = 0; bl < 2; ++bl) {
                    int b32 = bh * 8 + bq * 2 + bl;
                    float rr = sigmoidf_(a[0][bl] + br);
                    float zz = sigmoidf_(a[0][2 + bl] + bz);
                    float nn = tanhf_(a[0][4 + bl] + bxn + rr * (a[0][6 + bl] + bhn));
                    float hp = hprev[b32 * 128 + u];
                    ex_store(hout + b32 * 128 + u, (1.f - zz) * nn + zz * hp);
                }
            }
            asm volatile("s_waitcnt vmcnt(0)" ::: "memory");
            __syncthreads();
            if (tid == 0) flag_st(arr_own + us, t + 1);
        }
    } else {
        // ---- layer 4: in=128, H=256, + projection ----
        float* wlds = smem;             // 32 x 772
        float* hin = smem + 24704;      // 32 x 128
        float* hprev = smem + 28800;    // 32 x 256
        float* xb = smem + 36992;       // 4 x 64 x 8
        {
            const float* srcw = wA_hh4 + (size_t)us * 32 * 768;
            for (int i = tid; i < 24576; i += 512) {
                int uu = i / 768, r = i - uu * 768;
                wlds[uu * 772 + r] = srcw[i];
            }
        }
        __syncthreads();
        const int iown = ((kl & 1) << 1) | ((kl >> 1) & 1);
        const int k2 = (kl >> 2) & 1;
        const int ul = usl + 8 * iown;
        const int u = us * 32 + ul;
        const float* wbi = wA_ih4 + (size_t)(us * 32 + usl) * 384;  // global
        const float* wbh = wlds + usl * 772;
        const float br = b_ih4[u] + b_hh4[u];
        const float bz = b_ih4[u + 256] + b_hh4[u + 256];
        const float bxn = b_ih4[u + 512];
        const float bhn = b_hh4[u + 512];
        const float wo = w_out[u];
        for (int t = 0; t < 1024; ++t) {
            pollwait(pT, t + dT, aT, fcT);   // upstream only
            stage8<128>(hin + bh * 1024, h3r + (size_t)(t & 3) * 4096 + bh * 1024);
            float a[8][16] = {};
            dotA<128, 384, 2, 16>(wbi, hin + bh * 1024, kh, kl, a);  // xn -> 8..11
            pollwait(pM, t, aM, fcM);
            if (t > 0) stage8<256>(hprev + bh * 2048,
                                   h4r + (size_t)((t - 1) & 3) * 8192 + bh * 2048);
            else       zero8<256>(hprev + bh * 2048);
            dotA<256, 772, 3, 16>(wbh, hprev + bh * 2048, kh, kl, a); // hn -> 12..15
            rscat8<16>(a, kl);
            khmerge<16, 0, 8>(xb, a, w, lane);
            khmerge<16, 8, 8>(xb, a, w, lane);
            float pk[4] = {0.f, 0.f, 0.f, 0.f};
            if (w < 4) {
                float* hout = h4r + (size_t)(t & 3) * 8192;
                #pragma unroll
                for (int bl = 0; bl < 4; ++bl) {
                    int b32 = bh * 8 + k2 * 4 + bl;
                    float rr = sigmoidf_(a[0][bl] + br);
                    float zz = sigmoidf_(a[0][4 + bl] + bz);
                    float nn = tanhf_(a[0][8 + bl] + bxn + rr * (a[0][12 + bl] + bhn));
                    float hp = hprev[b32 * 256 + u];
                    float hnew = (1.f - zz) * nn + zz * hp;
                    ex_store(hout + b32 * 256 + u, hnew);
                    pk[bl] = wo * hnew;
                }
                // sum over units: usl bits (8,16,32) + iown bits (1,2); keep k2
                #pragma unroll
                for (int bl = 0; bl < 4; ++bl) {
                    pk[bl] += __shfl_xor(pk[bl], 1, 64);
                    pk[bl] += __shfl_xor(pk[bl], 2, 64);
                    pk[bl] += __shfl_xor(pk[bl], 8, 64);
                    pk[bl] += __shfl_xor(pk[bl], 16, 64);
                    pk[bl] += __shfl_xor(pk[bl], 32, 64);
                }
            }
            asm volatile("s_waitcnt vmcnt(0)" ::: "memory");
            __syncthreads();
            if (tid == 0) flag_st(arr_own + us, t + 1);
            if (w < 4 && (lane & 59) == 0) {   // lanes 0 (k2=0), 4 (k2=1)
                #pragma unroll
                for (int bl = 0; bl < 4; ++bl) {
                    float v = pk[bl];
                    if (us == 0) v += b_out[0];
                    atomicAdd(out + (size_t)(bg * 32 + bh * 8 +
                              ((lane >> 2) & 1) * 4 + bl) * 1024 + t, v);
                }
            }
        }
    }
}

extern "C" void kernel_launch(void* const* d_in, const int* in_sizes, int n_in,
                              void* d_out, int out_size, void* d_ws, size_t ws_size,
                              hipStream_t stream) {
    const float* x     = (const float*)d_in[0];
    const float* w_ih1 = (const float*)d_in[1];
    const float* w_hh1 = (const float*)d_in[2];
    const float* b_ih1 = (const float*)d_in[3];
    const float* b_hh1 = (const float*)d_in[4];
    const float* w_ih2 = (const float*)d_in[5];
    const float* w_hh2 = (const float*)d_in[6];
    const float* b_ih2 = (const float*)d_in[7];
    const float* b_hh2 = (const float*)d_in[8];
    const float* w_ih3 = (const float*)d_in[9];
    const float* w_hh3 = (const float*)d_in[10];
    const float* b_ih3 = (const float*)d_in[11];
    const float* b_hh3 = (const float*)d_in[12];
    const float* w_ih4 = (const float*)d_in[13];
    const float* w_hh4 = (const float*)d_in[14];
    const float* b_ih4 = (const float*)d_in[15];
    const float* b_hh4 = (const float*)d_in[16];
    const float* w_out = (const float*)d_in[17];
    const float* b_out = (const float*)d_in[18];

    float* ws = (float*)d_ws;
    float* wA_hh1 = ws;                  // 196608
    float* wA_ih2 = wA_hh1 + 196608;     //  98304
    float* wA_hh2 = wA_ih2 + 98304;      //  49152
    float* wA_ih3 = wA_hh2 + 49152;      //  49152
    float* wA_hh3 = wA_ih3 + 49152;      //  49152
    float* wA_ih4 = wA_hh3 + 49152;      //  98304
    float* wA_hh4 = wA_ih4 + 98304;      // 196608
    float* ex     = wA_hh4 + 196608;     // 786432 (8 bg x 98304)
    int*   flags  = (int*)(ex + 786432); // 8 x 128 ints

    (void)hipMemsetAsync(flags, 0, 1024 * sizeof(int), stream);
    (void)hipMemsetAsync(d_out, 0, 256 * 1024 * sizeof(float), stream);

    prep_k<<<768, 256, 0, stream>>>(w_hh1, wA_hh1, 256, 256);
    prep_k<<<384, 256, 0, stream>>>(w_ih2, wA_ih2, 128, 256);
    prep_k<<<192, 256, 0, stream>>>(w_hh2, wA_hh2, 128, 128);
    prep_k<<<192, 256, 0, stream>>>(w_ih3, wA_ih3, 128, 128);
    prep_k<<<192, 256, 0, stream>>>(w_hh3, wA_hh3, 128, 128);
    prep_k<<<384, 256, 0, stream>>>(w_ih4, wA_ih4, 256, 128);
    prep_k<<<768, 256, 0, stream>>>(w_hh4, wA_hh4, 256, 256);

    // 152.5KB dynamic LDS (39040 floats): 1 block/CU; grid=256 co-resident;
    // 512 threads => 8 waves = 2 waves/SIMD.
    const int dyn_lds = 39040 * (int)sizeof(float);
    (void)hipFuncSetAttribute((const void*)gru_pipe_kernel,
                              hipFuncAttributeMaxDynamicSharedMemorySize, dyn_lds);

    gru_pipe_kernel<<<256, 512, dyn_lds, stream>>>(
        x, w_ih1, b_ih1, b_hh1, b_ih2, b_hh2, b_ih3, b_hh3, b_ih4, b_hh4,
        wA_hh1, wA_ih2, wA_hh2, wA_ih3, wA_hh3, wA_ih4, wA_hh4,
        w_out, b_out, flags, ex, (float*)d_out);
}

// Round 6
// 18911.821 us; speedup vs baseline: 1.0986x; 1.0986x over previous
//
#include <hip/hip_runtime.h>
#include <math.h>

// ---------------------------------------------------------------------------
// R17 = R16 resubmitted verbatim (round 5 was an infra failure: "MI355X
// container failed twice" -- no counters, nothing to post-mortem).
//
// R16: R11's proven skeleton + latency-overlap package. Evidence: R15 doubled
// occupancy with zero period change => serial-chain-bound, not throughput-
// bound. R11's chain = ~5 LLC RTs/step (upstream flag, hin stage, peer flag,
// hprev stage, store drain) + ~11Kcy VALU. This round removes 3 of the 5 RTs
// without touching the proven dot3 / transport:
//   1) polls: per-wave lanes (lane<8 upstream/peer, 8..15 downstream),
//      monotone per-lane flag cache, sleep EVERY spin (R11 pacing -- R13/R15's
//      hot-spin correlates with the 50-62ms dispatch modes).
//   2) hin register-prefetch (stages 1-3): gate on CACHED fcT >= t+2, issue
//      loads right after dot_ih => they fly during dot_hh+epilogue; consumed
//      next iteration as pure LDS writes. pollT skipped when prefetched.
//      (R13-proven correctness; ring backpressure makes slot overwrite safe.)
//   3) non-blocking flag refreshes: issue peer refresh after the staging
//      barrier and upstream refresh after dot_ih; MERGE only at the use
//      point several Kcy later. Poll RTs leave the serial chain.
// Dots/addressing: R11's exact conflict-free pattern (one lane-coordinate
// varies per LDS read, 8-lane broadcast on the other; R14/R15's two-coordinate
// variants caused 314M-988M bank conflicts). Transport unchanged: sc0 sc1 LLC
// loads, agent-scope atomic stores, vmcnt(0)+barrier before flag publish.
// ---------------------------------------------------------------------------

__device__ __forceinline__ float sigmoidf_(float v) {
    return 1.0f / (1.0f + __expf(-v));
}
__device__ __forceinline__ float tanhf_(float v) {
    float e = __expf(2.0f * v);
    return 1.0f - 2.0f / (e + 1.0f);
}

// src[(g*H+u)*J + j] -> dst[(u*3+g)*J + j]
__global__ void prep_k(const float* __restrict__ src, float* __restrict__ dst,
                       int H, int J) {
    int idx = blockIdx.x * 256 + threadIdx.x;
    int total = 3 * H * J;
    if (idx < total) {
        int g = idx / (H * J);
        int rem = idx - g * H * J;
        int u = rem / J;
        int j = rem - u * J;
        dst[(u * 3 + g) * J + j] = src[(g * H + u) * J + j];
    }
}

// ---- transport primitives --------------------------------------------------

__device__ __forceinline__ void flag_st(int* p, int v) {
    __hip_atomic_store(p, v, __ATOMIC_RELAXED, __HIP_MEMORY_SCOPE_AGENT);
}
__device__ __forceinline__ int flag_ld(const int* p) {
    return __hip_atomic_load(p, __ATOMIC_RELAXED, __HIP_MEMORY_SCOPE_AGENT);
}
__device__ __forceinline__ void ex_store(float* p, float v) {
    __hip_atomic_store(p, v, __ATOMIC_RELAXED, __HIP_MEMORY_SCOPE_AGENT);
}

// Per-wave cached poll, barrier-less, sleep-paced (R11 pacing). Monotone
// flags: a satisfied poll is a few VALU ops, no memory traffic.
__device__ __forceinline__ void pollw(const int* p, int tgt, bool active,
                                      int& fc) {
    bool need = active && (fc < tgt);
    if (!__any(need)) return;
    int spins = 0;
    while (true) {
        if (need) { fc = flag_ld(p); need = (fc < tgt); }
        if (!__any(need)) return;
        if (++spins > 200000) return;  // bounded: degrade to absmax diagnostic
        __builtin_amdgcn_s_sleep(1);
    }
}

// ---- staging: ring -> regs -> LDS (split so prefetch can hold regs) -------

template <int J>
__device__ __forceinline__ void stage_load(float4* r, const float* src) {
    constexpr int NF4 = (32 * J) / 1024;
    #pragma unroll
    for (int k = 0; k < NF4; ++k) {
        const float* p = src + (size_t)(k * 256 + threadIdx.x) * 4;
        asm volatile("global_load_dwordx4 %0, %1, off sc0 sc1"
                     : "=v"(r[k]) : "v"(p) : "memory");
    }
}

template <int J>
__device__ __forceinline__ void stage_write(const float4* r, float* dst) {
    constexpr int NF4 = (32 * J) / 1024;
    constexpr int LJ = (J == 256) ? 8 : 7;
    #pragma unroll
    for (int k = 0; k < NF4; ++k) {
        int i = (k * 256 + threadIdx.x) * 4;
        int b = i >> LJ;
        int j = i & (J - 1);
        *(float4*)(dst + b * (J + 4) + j) = r[k];
    }
}

template <int J>
__device__ __forceinline__ void stageX(float* dst, const float* src) {
    float4 tmp[(32 * J) / 1024];
    stage_load<J>(tmp, src);
    asm volatile("s_waitcnt vmcnt(0)" ::: "memory");
    stage_write<J>(tmp, dst);
}

template <int J>
__device__ __forceinline__ void zero32(float* dst) {
    for (int i = threadIdx.x; i < 32 * (J + 4); i += 256) dst[i] = 0.0f;
}

// acc{r,z,c} += w{R,Z,N} . h[row] for KB batch rows (row = b0 + k*(32/KB)).
// R11's conflict-free pattern: w-addr varies only via ul (broadcast over b0
// group), h-addr varies only via b0 (broadcast over ul group).
template <int KB, int J>
__device__ __forceinline__ void dot3(const float* __restrict__ w3,
                                     const float* __restrict__ hst, int b0,
                                     float* ar, float* az, float* ac) {
    const float4* wr = (const float4*)w3;
    const float4* wz = (const float4*)(w3 + J);
    const float4* wn = (const float4*)(w3 + 2 * J);
    const float* rows[KB];
    #pragma unroll
    for (int k = 0; k < KB; ++k) rows[k] = hst + (b0 + k * (32 / KB)) * (J + 4);
    #pragma unroll 4
    for (int j4 = 0; j4 < J / 4; ++j4) {
        float4 a = wr[j4];
        float4 c = wz[j4];
        float4 d = wn[j4];
        #pragma unroll
        for (int k = 0; k < KB; ++k) {
            float4 hv = *(const float4*)(rows[k] + j4 * 4);
            ar[k] = fmaf(hv.x, a.x, ar[k]); ar[k] = fmaf(hv.y, a.y, ar[k]);
            ar[k] = fmaf(hv.z, a.z, ar[k]); ar[k] = fmaf(hv.w, a.w, ar[k]);
            az[k] = fmaf(hv.x, c.x, az[k]); az[k] = fmaf(hv.y, c.y, az[k]);
            az[k] = fmaf(hv.z, c.z, az[k]); az[k] = fmaf(hv.w, c.w, az[k]);
            ac[k] = fmaf(hv.x, d.x, ac[k]); ac[k] = fmaf(hv.y, d.y, ac[k]);
            ac[k] = fmaf(hv.z, d.z, ac[k]); ac[k] = fmaf(hv.w, d.w, ac[k]);
        }
    }
}

__global__ __launch_bounds__(256) void gru_pipe_kernel(
    const float* __restrict__ x,
    const float* __restrict__ w_ih1,
    const float* __restrict__ b_ih1, const float* __restrict__ b_hh1,
    const float* __restrict__ b_ih2, const float* __restrict__ b_hh2,
    const float* __restrict__ b_ih3, const float* __restrict__ b_hh3,
    const float* __restrict__ b_ih4, const float* __restrict__ b_hh4,
    const float* __restrict__ wA_hh1,  // [256][3][256]
    const float* __restrict__ wA_ih2,  // [128][3][256]
    const float* __restrict__ wA_hh2,  // [128][3][128]
    const float* __restrict__ wA_ih3,  // [128][3][128]
    const float* __restrict__ wA_hh3,  // [128][3][128]
    const float* __restrict__ wA_ih4,  // [256][3][128]
    const float* __restrict__ wA_hh4,  // [256][3][256]
    const float* __restrict__ w_out, const float* __restrict__ b_out,
    int* __restrict__ flags,  // [8 bg][4 stages x 32 ints (128B line)]
    float* __restrict__ ex,   // [8 bg][98304] h rings
    float* __restrict__ out)  // [256][1024] pre-zeroed
{
    const int tid = threadIdx.x;
    const int lane = tid & 63;
    extern __shared__ float smem[];
    __shared__ float xs[32];
    __shared__ float wsum[4][4][8];

    const int bg = blockIdx.x & 7;        // batch group (32 rows)
    const int rest = blockIdx.x >> 3;
    const int s = rest >> 3;              // stage 0..3
    const int us = rest & 7;              // unit slice 0..7

    int* fb = flags + bg * 128;           // 4 lines x 32 ints
    int* arr_own = fb + s * 32;           // this stage's 8 seq numbers

    // per-lane poll assignments (every wave, lane-based)
    const int* pT = arr_own; int dT = 0; bool aT = false;
    const int* pM = arr_own; bool aM = false;
    if (lane < 8) {
        if (s > 0) { pT = fb + (s - 1) * 32 + lane; dT = 1; aT = true; }
        pM = arr_own + lane; aM = true;
    } else if (lane < 16) {
        if (s < 3) { pT = fb + (s + 1) * 32 + (lane - 8); dT = -3; aT = true; }
    }
    const bool aUp = (s > 0) && (lane < 8);
    int fcT = 0, fcM = 0;  // monotone flag caches

    float* exb = ex + (size_t)bg * 98304;
    float* h1r = exb;            // 4 slots x 32 x 256
    float* h2r = exb + 32768;    // 4 x 32 x 128
    float* h3r = exb + 49152;
    float* h4r = exb + 65536;

    if (s == 0) {
        // ---- layer 1: in=1 scalar, H=256, 32 units/slice, KB=4 ----
        float* wlds = smem;            // [32][772]
        float* hprev = smem + 24704;   // [32][260]
        {
            const float* srcw = wA_hh1 + (size_t)us * 32 * 768;
            for (int i = tid; i < 24576; i += 256) {
                int uu = i / 768, r = i - uu * 768;
                wlds[uu * 772 + r] = srcw[i];
            }
        }
        __syncthreads();
        const int ul = tid >> 3, b0 = tid & 7;
        const int u = us * 32 + ul;
        const float* wh = wlds + ul * 772;
        const float br = b_ih1[u] + b_hh1[u];
        const float bz = b_ih1[u + 256] + b_hh1[u + 256];
        const float bxn = b_ih1[u + 512];
        const float bhn = b_hh1[u + 512];
        const float wir = w_ih1[u], wiz = w_ih1[u + 256], win = w_ih1[u + 512];
        int freshM = 0;
        for (int t = 0; t < 1024; ++t) {
            pollw(pT, t + dT, aT, fcT);            // downstream backpressure
            if (tid < 32) xs[tid] = x[(size_t)(bg * 32 + tid) * 1024 + t];
            if (aM && freshM > fcM) fcM = freshM;  // merge hoisted refresh
            pollw(pM, t, aM, fcM);                 // peers done t-1
            if (t > 0) stageX<256>(hprev, h1r + (size_t)((t - 1) & 3) * 8192);
            else       zero32<256>(hprev);
            __syncthreads();
            int freshT = aT ? flag_ld(pT) : 0;     // non-blocking refresh
            float ar[4], az[4], axn[4], ahn[4];
            #pragma unroll
            for (int k = 0; k < 4; ++k) {
                float xv = xs[b0 + 8 * k];
                ar[k] = br + xv * wir; az[k] = bz + xv * wiz;
                axn[k] = bxn + xv * win; ahn[k] = bhn;
            }
            dot3<4, 256>(wh, hprev, b0, ar, az, ahn);
            float* hout = h1r + (size_t)(t & 3) * 8192;
            #pragma unroll
            for (int k = 0; k < 4; ++k) {
                int b = b0 + 8 * k;
                float hp = hprev[b * 260 + u];
                float r = sigmoidf_(ar[k]);
                float z = sigmoidf_(az[k]);
                float n = tanhf_(axn[k] + r * ahn[k]);
                ex_store(hout + b * 256 + u, (1.f - z) * n + z * hp);
            }
            if (aT && freshT > fcT) fcT = freshT;  // merge (had dot time)
            asm volatile("s_waitcnt vmcnt(0)" ::: "memory");  // h at LLC
            __syncthreads();
            if (tid == 0) flag_st(arr_own + us, t + 1);
            freshM = aM ? flag_ld(pM) : 0;         // issue for next pollM
        }
    } else if (s == 1) {
        // ---- layer 2: in=256, H=128, 16 units/slice, KB=2 ----
        float* wlds = smem;            // [16][388]
        float* hin = smem + 6208;      // [32][260]
        float* hprev = smem + 14528;   // [32][132]
        {
            const float* srcw = wA_hh2 + (size_t)us * 16 * 384;
            for (int i = tid; i < 6144; i += 256) {
                int uu = i / 384, r = i - uu * 384;
                wlds[uu * 388 + r] = srcw[i];
            }
        }
        __syncthreads();
        const int ul = tid >> 4, b0 = tid & 15;
        const int u = us * 16 + ul;
        const float* wi = wA_ih2 + (size_t)u * 768;
        const float* wh = wlds + ul * 388;
        const float br = b_ih2[u] + b_hh2[u];
        const float bz = b_ih2[u + 128] + b_hh2[u + 128];
        const float bxn = b_ih2[u + 256];
        const float bhn = b_hh2[u + 256];
        float4 pregs[8];
        bool pf = false;
        for (int t = 0; t < 1024; ++t) {
            pollw(pT, t + dT, aT && (lane >= 8 || !pf), fcT);
            if (pf) stage_write<256>(pregs, hin);
            else    stageX<256>(hin, h1r + (size_t)(t & 3) * 8192);
            __syncthreads();
            int freshM = aM ? flag_ld(pM) : 0;     // hoisted peer refresh
            float ar[2] = {br, br}, az[2] = {bz, bz};
            float axn[2] = {bxn, bxn}, ahn[2] = {bhn, bhn};
            dot3<2, 256>(wi, hin, b0, ar, az, axn);
            // prefetch hin(t+1): cached gate, loads fly through dot_hh
            bool pf_n = false;
            if (t < 1023) {
                pf_n = __all(!aUp || fcT >= t + 2);
                if (pf_n) stage_load<256>(pregs, h1r + (size_t)((t + 1) & 3) * 8192);
            }
            int freshT = aT ? flag_ld(pT) : 0;
            if (aM && freshM > fcM) fcM = freshM;  // merge (had dot_ih time)
            pollw(pM, t, aM, fcM);
            if (t > 0) stageX<128>(hprev, h2r + (size_t)((t - 1) & 3) * 4096);
            else       zero32<128>(hprev);
            __syncthreads();
            dot3<2, 128>(wh, hprev, b0, ar, az, ahn);
            float* hout = h2r + (size_t)(t & 3) * 4096;
            #pragma unroll
            for (int k = 0; k < 2; ++k) {
                int b = b0 + 16 * k;
                float hp = hprev[b * 132 + u];
                float r = sigmoidf_(ar[k]);
                float z = sigmoidf_(az[k]);
                float n = tanhf_(axn[k] + r * ahn[k]);
                ex_store(hout + b * 128 + u, (1.f - z) * n + z * hp);
            }
            if (aT && freshT > fcT) fcT = freshT;
            pf = pf_n;
            asm volatile("s_waitcnt vmcnt(0)" ::: "memory");
            __syncthreads();
            if (tid == 0) flag_st(arr_own + us, t + 1);
        }
    } else if (s == 2) {
        // ---- layer 3: in=128, H=128, 16 units/slice, KB=2 ----
        float* wlds = smem;            // [16][388]
        float* hin = smem + 6208;      // [32][132]
        float* hprev = smem + 10432;   // [32][132]
        {
            const float* srcw = wA_hh3 + (size_t)us * 16 * 384;
            for (int i = tid; i < 6144; i += 256) {
                int uu = i / 384, r = i - uu * 384;
                wlds[uu * 388 + r] = srcw[i];
            }
        }
        __syncthreads();
        const int ul = tid >> 4, b0 = tid & 15;
        const int u = us * 16 + ul;
        const float* wi = wA_ih3 + (size_t)u * 384;
        const float* wh = wlds + ul * 388;
        const float br = b_ih3[u] + b_hh3[u];
        const float bz = b_ih3[u + 128] + b_hh3[u + 128];
        const float bxn = b_ih3[u + 256];
        const float bhn = b_hh3[u + 256];
        float4 pregs[4];
        bool pf = false;
        for (int t = 0; t < 1024; ++t) {
            pollw(pT, t + dT, aT && (lane >= 8 || !pf), fcT);
            if (pf) stage_write<128>(pregs, hin);
            else    stageX<128>(hin, h2r + (size_t)(t & 3) * 4096);
            __syncthreads();
            int freshM = aM ? flag_ld(pM) : 0;
            float ar[2] = {br, br}, az[2] = {bz, bz};
            float axn[2] = {bxn, bxn}, ahn[2] = {bhn, bhn};
            dot3<2, 128>(wi, hin, b0, ar, az, axn);
            bool pf_n = false;
            if (t < 1023) {
                pf_n = __all(!aUp || fcT >= t + 2);
                if (pf_n) stage_load<128>(pregs, h2r + (size_t)((t + 1) & 3) * 4096);
            }
            int freshT = aT ? flag_ld(pT) : 0;
            if (aM && freshM > fcM) fcM = freshM;
            pollw(pM, t, aM, fcM);
            if (t > 0) stageX<128>(hprev, h3r + (size_t)((t - 1) & 3) * 4096);
            else       zero32<128>(hprev);
            __syncthreads();
            dot3<2, 128>(wh, hprev, b0, ar, az, ahn);
            float* hout = h3r + (size_t)(t & 3) * 4096;
            #pragma unroll
            for (int k = 0; k < 2; ++k) {
                int b = b0 + 16 * k;
                float hp = hprev[b * 132 + u];
                float r = sigmoidf_(ar[k]);
                float z = sigmoidf_(az[k]);
                float n = tanhf_(axn[k] + r * ahn[k]);
                ex_store(hout + b * 128 + u, (1.f - z) * n + z * hp);
            }
            if (aT && freshT > fcT) fcT = freshT;
            pf = pf_n;
            asm volatile("s_waitcnt vmcnt(0)" ::: "memory");
            __syncthreads();
            if (tid == 0) flag_st(arr_own + us, t + 1);
        }
    } else {
        // ---- layer 4: in=128, H=256, 32 units/slice, KB=4, + projection ----
        float* wlds = smem;            // [32][772]
        float* hin = smem + 24704;     // [32][132]
        float* hprev = smem + 28928;   // [32][260]
        {
            const float* srcw = wA_hh4 + (size_t)us * 32 * 768;
            for (int i = tid; i < 24576; i += 256) {
                int uu = i / 768, r = i - uu * 768;
                wlds[uu * 772 + r] = srcw[i];
            }
        }
        __syncthreads();
        const int ul = tid >> 3, b0 = tid & 7;
        const int u = us * 32 + ul;
        const float* wi = wA_ih4 + (size_t)u * 384;
        const float* wh = wlds + ul * 772;
        const float br = b_ih4[u] + b_hh4[u];
        const float bz = b_ih4[u + 256] + b_hh4[u + 256];
        const float bxn = b_ih4[u + 512];
        const float bhn = b_hh4[u + 512];
        const float wo = w_out[u];
        float4 pregs[4];
        bool pf = false;
        for (int t = 0; t < 1024; ++t) {
            pollw(pT, t + dT, aT && !pf, fcT);   // upstream only
            if (pf) stage_write<128>(pregs, hin);
            else    stageX<128>(hin, h3r + (size_t)(t & 3) * 4096);
            __syncthreads();
            int freshM = aM ? flag_ld(pM) : 0;
            float ar[4], az[4], axn[4], ahn[4];
            #pragma unroll
            for (int k = 0; k < 4; ++k) {
                ar[k] = br; az[k] = bz; axn[k] = bxn; ahn[k] = bhn;
            }
            dot3<4, 128>(wi, hin, b0, ar, az, axn);
            bool pf_n = false;
            if (t < 1023) {
                pf_n = __all(!aUp || fcT >= t + 2);
                if (pf_n) stage_load<128>(pregs, h3r + (size_t)((t + 1) & 3) * 4096);
            }
            int freshT = aT ? flag_ld(pT) : 0;
            if (aM && freshM > fcM) fcM = freshM;
            pollw(pM, t, aM, fcM);
            if (t > 0) stageX<256>(hprev, h4r + (size_t)((t - 1) & 3) * 8192);
            else       zero32<256>(hprev);
            __syncthreads();
            dot3<4, 256>(wh, hprev, b0, ar, az, ahn);
            float* hout = h4r + (size_t)(t & 3) * 8192;
            float pk[4];
            #pragma unroll
            for (int k = 0; k < 4; ++k) {
                int b = b0 + 8 * k;
                float hp = hprev[b * 260 + u];
                float r = sigmoidf_(ar[k]);
                float z = sigmoidf_(az[k]);
                float n = tanhf_(axn[k] + r * ahn[k]);
                float hnew = (1.f - z) * n + z * hp;
                ex_store(hout + b * 256 + u, hnew);
                pk[k] = wo * hnew;
            }
            #pragma unroll
            for (int k = 0; k < 4; ++k) {
                pk[k] += __shfl_xor(pk[k], 8, 64);
                pk[k] += __shfl_xor(pk[k], 16, 64);
                pk[k] += __shfl_xor(pk[k], 32, 64);
            }
            if ((tid & 63) < 8) {
                int w = tid >> 6;
                #pragma unroll
                for (int k = 0; k < 4; ++k) wsum[w][k][tid & 7] = pk[k];
            }
            if (aT && freshT > fcT) fcT = freshT;
            pf = pf_n;
            asm volatile("s_waitcnt vmcnt(0)" ::: "memory");
            __syncthreads();
            if (tid == 0) flag_st(arr_own + us, t + 1);
            if (tid < 32) {
                int k = tid >> 3, bb = tid & 7;
                float ssum = wsum[0][k][bb] + wsum[1][k][bb] +
                             wsum[2][k][bb] + wsum[3][k][bb];
                if (us == 0) ssum += b_out[0];
                atomicAdd(out + (size_t)(bg * 32 + bb + 8 * k) * 1024 + t, ssum);
            }
        }
    }
}

extern "C" void kernel_launch(void* const* d_in, const int* in_sizes, int n_in,
                              void* d_out, int out_size, void* d_ws, size_t ws_size,
                              hipStream_t stream) {
    const float* x     = (const float*)d_in[0];
    const float* w_ih1 = (const float*)d_in[1];
    const float* w_hh1 = (const float*)d_in[2];
    const float* b_ih1 = (const float*)d_in[3];
    const float* b_hh1 = (const float*)d_in[4];
    const float* w_ih2 = (const float*)d_in[5];
    const float* w_hh2 = (const float*)d_in[6];
    const float* b_ih2 = (const float*)d_in[7];
    const float* b_hh2 = (const float*)d_in[8];
    const float* w_ih3 = (const float*)d_in[9];
    const float* w_hh3 = (const float*)d_in[10];
    const float* b_ih3 = (const float*)d_in[11];
    const float* b_hh3 = (const float*)d_in[12];
    const float* w_ih4 = (const float*)d_in[13];
    const float* w_hh4 = (const float*)d_in[14];
    const float* b_ih4 = (const float*)d_in[15];
    const float* b_hh4 = (const float*)d_in[16];
    const float* w_out = (const float*)d_in[17];
    const float* b_out = (const float*)d_in[18];

    float* ws = (float*)d_ws;
    float* wA_hh1 = ws;                  // 196608
    float* wA_ih2 = wA_hh1 + 196608;     //  98304
    float* wA_hh2 = wA_ih2 + 98304;      //  49152
    float* wA_ih3 = wA_hh2 + 49152;      //  49152
    float* wA_hh3 = wA_ih3 + 49152;      //  49152
    float* wA_ih4 = wA_hh3 + 49152;      //  98304
    float* wA_hh4 = wA_ih4 + 98304;      // 196608
    float* ex     = wA_hh4 + 196608;     // 786432 (8 bg x 98304)
    int*   flags  = (int*)(ex + 786432); // 8 x 128 ints

    (void)hipMemsetAsync(flags, 0, 1024 * sizeof(int), stream);
    (void)hipMemsetAsync(d_out, 0, 256 * 1024 * sizeof(float), stream);

    prep_k<<<768, 256, 0, stream>>>(w_hh1, wA_hh1, 256, 256);
    prep_k<<<384, 256, 0, stream>>>(w_ih2, wA_ih2, 128, 256);
    prep_k<<<192, 256, 0, stream>>>(w_hh2, wA_hh2, 128, 128);
    prep_k<<<192, 256, 0, stream>>>(w_ih3, wA_ih3, 128, 128);
    prep_k<<<192, 256, 0, stream>>>(w_hh3, wA_hh3, 128, 128);
    prep_k<<<384, 256, 0, stream>>>(w_ih4, wA_ih4, 256, 128);
    prep_k<<<768, 256, 0, stream>>>(w_hh4, wA_hh4, 256, 256);

    // 149KB dynamic LDS: 1 block/CU; grid=256 => all blocks co-resident.
    const int dyn_lds = 37248 * (int)sizeof(float);
    (void)hipFuncSetAttribute((const void*)gru_pipe_kernel,
                              hipFuncAttributeMaxDynamicSharedMemorySize, dyn_lds);

    gru_pipe_kernel<<<256, 256, dyn_lds, stream>>>(
        x, w_ih1, b_ih1, b_hh1, b_ih2, b_hh2, b_ih3, b_hh3, b_ih4, b_hh4,
        wA_hh1, wA_ih2, wA_hh2, wA_ih3, wA_hh3, wA_ih4, wA_hh4,
        w_out, b_out, flags, ex, (float*)d_out);
}